// Round 11
// baseline (989.467 us; speedup 1.0000x reference)
//
#include <hip/hip_runtime.h>

#define NN 20000
#define DEG 16
#define HDIM 128
#define GDIM 512

typedef __attribute__((ext_vector_type(8))) short bf16x8;
typedef __attribute__((ext_vector_type(4))) float f32x4;
typedef __attribute__((ext_vector_type(2))) unsigned u32x2;
typedef __attribute__((ext_vector_type(4))) unsigned u32x4;
typedef unsigned long long ull;

#define L2E  1.4426950408889634f
#define L2E2 2.8853900817779268f

__device__ __forceinline__ f32x4 mfma16(bf16x8 a, bf16x8 b, f32x4 c) {
    return __builtin_amdgcn_mfma_f32_16x16x32_bf16(a, b, c, 0, 0, 0);
}

__device__ __forceinline__ unsigned short f2bf(float f) {
    unsigned u = __builtin_bit_cast(unsigned, f);
    u += 0x7FFFu + ((u >> 16) & 1u);
    return (unsigned short)(u >> 16);
}

__device__ __forceinline__ unsigned cvtpk(float lo, float hi) {
    unsigned r;
    asm("v_cvt_pk_bf16_f32 %0, %1, %2" : "=v"(r) : "v"(lo), "v"(hi));
    return r;
}

__device__ __forceinline__ float bfhi(unsigned u) { return __builtin_bit_cast(float, u & 0xFFFF0000u); }
__device__ __forceinline__ float bflo(unsigned u) { return __builtin_bit_cast(float, u << 16); }

__device__ __forceinline__ void barrier_lgkm() {
    asm volatile("s_waitcnt lgkmcnt(0)\ns_barrier" ::: "memory");
}

__device__ __forceinline__ float sig_pre(float x) {     // x pre-scaled by log2e
    return __builtin_amdgcn_rcpf(1.f + __builtin_amdgcn_exp2f(-x));
}
__device__ __forceinline__ float tanh_pre2(float x2) {  // x2 pre-scaled by 2*log2e
    return 1.f - 2.f * __builtin_amdgcn_rcpf(__builtin_amdgcn_exp2f(x2) + 1.f);
}

// ---------------- weight convert + combined bias ----------------------------
struct CvtArgs {
    const float *wih[3], *whh[3], *wl[3], *wr[3], *bih[3], *bhh[3];
    unsigned short *dih[3], *dhh[3], *dl[3], *dr[3];
    float *dbias[3];
};

__global__ __launch_bounds__(256) void cvt_kernel(CvtArgs a) {
    int l = blockIdx.x / 642, b = blockIdx.x % 642, t = threadIdx.x;
    if (b < 256) {
        int i = b * 256 + t;
        float s = ((i >> 14) == 2) ? L2E2 : L2E;
        a.dih[l][i] = f2bf(a.wih[l][i] * s);
    } else if (b < 512) {
        int i = (b - 256) * 256 + t;
        float s = ((i >> 14) == 2) ? L2E2 : L2E;
        a.dhh[l][i] = f2bf(a.whh[l][i] * s);
    } else if (b < 576) {
        int i = (b - 512) * 256 + t;
        a.dl[l][i] = f2bf(a.wl[l][i]);
    } else if (b < 640) {
        int i = (b - 576) * 256 + t;
        a.dr[l][i] = f2bf(a.wr[l][i]);
    } else {
        int i = (b - 640) * 256 + t;
        float s = ((i >> 7) == 2) ? L2E2 : L2E;
        a.dbias[l][i] = (a.bih[l][i] + a.bhh[l][i]) * s;
    }
}

// ---- phase A (32-node tile): Xih from htile, interleaved bf16 out ----------
__device__ __forceinline__ void phaseA2(const unsigned short (*htile)[136],
        const unsigned short* __restrict__ wih, const float* __restrict__ biasc,
        unsigned short* __restrict__ xihb, int mbase, int cl, int qh, int k8, int wv) {
    bf16x8 a0[4], a1[4];
#pragma unroll
    for (int kt = 0; kt < 4; ++kt) {
        a0[kt] = *(const bf16x8*)(&htile[cl][kt * 32 + k8]);
        a1[kt] = *(const bf16x8*)(&htile[16 + cl][kt * 32 + k8]);
    }
#pragma unroll
    for (int nt = 0; nt < 2; ++nt) {
        const int col = wv * 32 + nt * 16 + cl;
        f32x4 acc0[4], acc1[4];
#pragma unroll
        for (int g = 0; g < 4; ++g) {
            acc0[g] = (f32x4){0.f, 0.f, 0.f, 0.f};
            acc1[g] = (f32x4){0.f, 0.f, 0.f, 0.f};
        }
#pragma unroll
        for (int g = 0; g < 4; ++g)
#pragma unroll
            for (int kt = 0; kt < 4; ++kt) {
                bf16x8 b = *(const bf16x8*)(wih + (g * 128 + col) * HDIM + kt * 32 + k8);
                acc0[g] = mfma16(a0[kt], b, acc0[g]);
                acc1[g] = mfma16(a1[kt], b, acc1[g]);
            }
        float bias[4];
#pragma unroll
        for (int g = 0; g < 4; ++g) bias[g] = biasc[g * 128 + col];
#pragma unroll
        for (int r = 0; r < 4; ++r) {
            unsigned p0 = cvtpk(acc0[0][r] + bias[0], acc0[1][r] + bias[1]);
            unsigned p1 = cvtpk(acc0[2][r] + bias[2], acc0[3][r] + bias[3]);
            *(ull*)(xihb + (size_t)(mbase + qh * 4 + r) * GDIM + col * 4) =
                (ull)p0 | ((ull)p1 << 32);
            unsigned q0 = cvtpk(acc1[0][r] + bias[0], acc1[1][r] + bias[1]);
            unsigned q1 = cvtpk(acc1[2][r] + bias[2], acc1[3][r] + bias[3]);
            *(ull*)(xihb + (size_t)(mbase + 16 + qh * 4 + r) * GDIM + col * 4) =
                (ull)q0 | ((ull)q1 << 32);
        }
    }
}

// ---- gemmA0: h0 = concat(x, emb[type]) (bf16) + Xih layer 0, 32 nodes ------
__global__ __launch_bounds__(256) void gemmA0_kernel(
        const float* __restrict__ x, const int* __restrict__ types,
        const float* __restrict__ emb, const unsigned short* __restrict__ wih,
        const float* __restrict__ biasc, unsigned short* __restrict__ h0,
        unsigned short* __restrict__ xihb) {
    __shared__ unsigned short htile[32][136];
    const int tid = threadIdx.x;
    const int lane = tid & 63, wv = tid >> 6;
    const int cl = lane & 15, qh = lane >> 4, k8 = qh * 8;
    const int mbase = blockIdx.x * 32;

    const int row = tid >> 3, c0 = (tid & 7) * 16;
    f32x4 u[4];
    if (c0 < 96) {
#pragma unroll
        for (int j = 0; j < 4; ++j)
            u[j] = *(const f32x4*)(x + (size_t)(mbase + row) * 96 + c0 + 4 * j);
    } else {
        int ty = types[mbase + row];
#pragma unroll
        for (int j = 0; j < 4; ++j)
            u[j] = *(const f32x4*)(emb + ty * 32 + (c0 - 96) + 4 * j);
    }
    u32x4 pk, pk2;
    pk[0]  = cvtpk(u[0][0], u[0][1]); pk[1]  = cvtpk(u[0][2], u[0][3]);
    pk[2]  = cvtpk(u[1][0], u[1][1]); pk[3]  = cvtpk(u[1][2], u[1][3]);
    pk2[0] = cvtpk(u[2][0], u[2][1]); pk2[1] = cvtpk(u[2][2], u[2][3]);
    pk2[2] = cvtpk(u[3][0], u[3][1]); pk2[3] = cvtpk(u[3][2], u[3][3]);
    *(u32x4*)(&htile[row][c0]) = pk;
    *(u32x4*)(&htile[row][c0 + 8]) = pk2;
    *(u32x4*)(h0 + (size_t)(mbase + row) * HDIM + c0) = pk;
    *(u32x4*)(h0 + (size_t)(mbase + row) * HDIM + c0 + 8) = pk2;
    __syncthreads();

    phaseA2(htile, wih, biasc, xihb, mbase, cl, qh, k8, wv);
}

// ---------------- fused per-node LSTM, 4-wave blocks ------------------------
// 256 threads / 4 waves, 16 nodes/block. Wave wv owns gate-dims [wv*32,wv*32+32)
// of all 4 gates (two 16-col groups A/B, 32 MFMAs/wave/step). Smaller blocks ->
// more resident blocks/CU (latency hiding) + half-width barriers. Round-10
// showed the kernel is latency/VALU bound, NOT L2-BW bound, so whh streams
// from L1/L2 (plain loads) and occupancy is the lever.
__global__ __launch_bounds__(256, 4) void lstm_kernel(
        const unsigned short* __restrict__ xihb, const unsigned short* __restrict__ whh,
        const int* __restrict__ esrc, unsigned short* __restrict__ agg) {
    __shared__ unsigned short hbuf[2][16][136];   // +8 pad
    __shared__ unsigned srcs_t[256];              // [t][node], pre-shifted <<10

    const int tid = threadIdx.x;
    const int lane = tid & 63, wv = tid >> 6;
    const int cl = lane & 15, qh = lane >> 4, k8 = qh * 8;
    const int colA = wv * 32 + cl;                // col group A
    const int base = blockIdx.x * 16;

    srcs_t[(tid & 15) * 16 + (tid >> 4)] = ((unsigned)esrc[base * DEG + tid]) << 10;
    __syncthreads();

    const unsigned short* wpA = whh + colA * HDIM + k8;        // B-frag bases
    const unsigned short* wpB = wpA + 16 * HDIM;
#define WA(g, kt) (*(const bf16x8*)(wpA + (g) * 128 * HDIM + (kt) * 32))
#define WB(g, kt) (*(const bf16x8*)(wpB + (g) * 128 * HDIM + (kt) * 32))

    const char* xpA = (const char*)xihb + (size_t)colA * 8u;
    const char* xpB = xpA + 128;
    float c0 = 0.f, c1 = 0.f, c2 = 0.f, c3 = 0.f;
    float c4 = 0.f, c5 = 0.f, c6 = 0.f, c7 = 0.f;
    unsigned pkA0 = 0, pkA1 = 0, pkB0 = 0, pkB1 = 0;
    ull ya0, ya1, ya2, ya3, ya4, ya5, ya6, ya7;
    ull yb0, yb1, yb2, yb3, yb4, yb5, yb6, yb7;

#define GATH(T, X0, X1, X2, X3, X4, X5, X6, X7) { \
    u32x4 sv = *(const u32x4*)&srcs_t[(T) * 16 + qh * 4]; \
    X0 = *(const ull*)(xpA + sv[0]); \
    X1 = *(const ull*)(xpA + sv[1]); \
    X2 = *(const ull*)(xpA + sv[2]); \
    X3 = *(const ull*)(xpA + sv[3]); \
    X4 = *(const ull*)(xpB + sv[0]); \
    X5 = *(const ull*)(xpB + sv[1]); \
    X6 = *(const ull*)(xpB + sv[2]); \
    X7 = *(const ull*)(xpB + sv[3]); }

    GATH(0, ya0, ya1, ya2, ya3, ya4, ya5, ya6, ya7)
    GATH(1, yb0, yb1, yb2, yb3, yb4, yb5, yb6, yb7)

#define UNP(X0, X1, X2, X3, A0, A1, A2, A3) \
    { unsigned lo = (unsigned)X0, hi = (unsigned)(X0 >> 32); \
      A0[0] = bflo(lo); A1[0] = bfhi(lo); A2[0] = bflo(hi); A3[0] = bfhi(hi); } \
    { unsigned lo = (unsigned)X1, hi = (unsigned)(X1 >> 32); \
      A0[1] = bflo(lo); A1[1] = bfhi(lo); A2[1] = bflo(hi); A3[1] = bfhi(hi); } \
    { unsigned lo = (unsigned)X2, hi = (unsigned)(X2 >> 32); \
      A0[2] = bflo(lo); A1[2] = bfhi(lo); A2[2] = bflo(hi); A3[2] = bfhi(hi); } \
    { unsigned lo = (unsigned)X3, hi = (unsigned)(X3 >> 32); \
      A0[3] = bflo(lo); A1[3] = bfhi(lo); A2[3] = bflo(hi); A3[3] = bfhi(hi); }

#define NONLIN(A0, A1, A2, A3, C0, C1, C2, C3, PK0, PK1) { \
    float i0 = sig_pre(A0[0]), f0 = sig_pre(A1[0]), g0 = tanh_pre2(A2[0]), o0 = sig_pre(A3[0]); \
    C0 = f0 * C0 + i0 * g0; float hv0 = o0 * tanh_pre2(C0 * L2E2); \
    float i1 = sig_pre(A0[1]), f1 = sig_pre(A1[1]), g1 = tanh_pre2(A2[1]), o1 = sig_pre(A3[1]); \
    C1 = f1 * C1 + i1 * g1; float hv1 = o1 * tanh_pre2(C1 * L2E2); \
    float i2 = sig_pre(A0[2]), f2 = sig_pre(A1[2]), g2 = tanh_pre2(A2[2]), o2 = sig_pre(A3[2]); \
    C2 = f2 * C2 + i2 * g2; float hv2 = o2 * tanh_pre2(C2 * L2E2); \
    float i3 = sig_pre(A0[3]), f3 = sig_pre(A1[3]), g3 = tanh_pre2(A2[3]), o3 = sig_pre(A3[3]); \
    C3 = f3 * C3 + i3 * g3; float hv3 = o3 * tanh_pre2(C3 * L2E2); \
    PK0 = cvtpk(hv0, hv1); \
    PK1 = cvtpk(hv2, hv3); }

#define STEP(T, X0, X1, X2, X3, X4, X5, X6, X7) { \
    f32x4 aA0, aA1, aA2, aA3, aB0, aB1, aB2, aB3; \
    UNP(X0, X1, X2, X3, aA0, aA1, aA2, aA3) \
    UNP(X4, X5, X6, X7, aB0, aB1, aB2, aB3) \
    if ((T) < 14) { GATH((T) + 2, X0, X1, X2, X3, X4, X5, X6, X7) } \
    if ((T) > 0) { \
        const unsigned short* hrow = &hbuf[((T) + 1) & 1][cl][k8]; \
        bf16x8 h0 = *(const bf16x8*)(hrow); \
        bf16x8 h1 = *(const bf16x8*)(hrow + 32); \
        bf16x8 h2 = *(const bf16x8*)(hrow + 64); \
        bf16x8 h3 = *(const bf16x8*)(hrow + 96); \
        aA0 = mfma16(h0, WA(0,0), aA0); aA0 = mfma16(h1, WA(0,1), aA0); \
        aA0 = mfma16(h2, WA(0,2), aA0); aA0 = mfma16(h3, WA(0,3), aA0); \
        aA1 = mfma16(h0, WA(1,0), aA1); aA1 = mfma16(h1, WA(1,1), aA1); \
        aA1 = mfma16(h2, WA(1,2), aA1); aA1 = mfma16(h3, WA(1,3), aA1); \
        aA2 = mfma16(h0, WA(2,0), aA2); aA2 = mfma16(h1, WA(2,1), aA2); \
        aA2 = mfma16(h2, WA(2,2), aA2); aA2 = mfma16(h3, WA(2,3), aA2); \
        aA3 = mfma16(h0, WA(3,0), aA3); aA3 = mfma16(h1, WA(3,1), aA3); \
        aA3 = mfma16(h2, WA(3,2), aA3); aA3 = mfma16(h3, WA(3,3), aA3); \
        aB0 = mfma16(h0, WB(0,0), aB0); aB0 = mfma16(h1, WB(0,1), aB0); \
        aB0 = mfma16(h2, WB(0,2), aB0); aB0 = mfma16(h3, WB(0,3), aB0); \
        aB1 = mfma16(h0, WB(1,0), aB1); aB1 = mfma16(h1, WB(1,1), aB1); \
        aB1 = mfma16(h2, WB(1,2), aB1); aB1 = mfma16(h3, WB(1,3), aB1); \
        aB2 = mfma16(h0, WB(2,0), aB2); aB2 = mfma16(h1, WB(2,1), aB2); \
        aB2 = mfma16(h2, WB(2,2), aB2); aB2 = mfma16(h3, WB(2,3), aB2); \
        aB3 = mfma16(h0, WB(3,0), aB3); aB3 = mfma16(h1, WB(3,1), aB3); \
        aB3 = mfma16(h2, WB(3,2), aB3); aB3 = mfma16(h3, WB(3,3), aB3); \
    } \
    NONLIN(aA0, aA1, aA2, aA3, c0, c1, c2, c3, pkA0, pkA1) \
    NONLIN(aB0, aB1, aB2, aB3, c4, c5, c6, c7, pkB0, pkB1) \
    if ((T) < 15) { \
        unsigned short* hp = &hbuf[(T) & 1][qh * 4][colA]; \
        hp[0]        = (unsigned short)pkA0; \
        hp[136]      = (unsigned short)(pkA0 >> 16); \
        hp[272]      = (unsigned short)pkA1; \
        hp[408]      = (unsigned short)(pkA1 >> 16); \
        hp[16]       = (unsigned short)pkB0; \
        hp[136 + 16] = (unsigned short)(pkB0 >> 16); \
        hp[272 + 16] = (unsigned short)pkB1; \
        hp[408 + 16] = (unsigned short)(pkB1 >> 16); \
        barrier_lgkm(); \
    } }

    STEP(0,  ya0, ya1, ya2, ya3, ya4, ya5, ya6, ya7)
    STEP(1,  yb0, yb1, yb2, yb3, yb4, yb5, yb6, yb7)
    STEP(2,  ya0, ya1, ya2, ya3, ya4, ya5, ya6, ya7)
    STEP(3,  yb0, yb1, yb2, yb3, yb4, yb5, yb6, yb7)
    STEP(4,  ya0, ya1, ya2, ya3, ya4, ya5, ya6, ya7)
    STEP(5,  yb0, yb1, yb2, yb3, yb4, yb5, yb6, yb7)
    STEP(6,  ya0, ya1, ya2, ya3, ya4, ya5, ya6, ya7)
    STEP(7,  yb0, yb1, yb2, yb3, yb4, yb5, yb6, yb7)
    STEP(8,  ya0, ya1, ya2, ya3, ya4, ya5, ya6, ya7)
    STEP(9,  yb0, yb1, yb2, yb3, yb4, yb5, yb6, yb7)
    STEP(10, ya0, ya1, ya2, ya3, ya4, ya5, ya6, ya7)
    STEP(11, yb0, yb1, yb2, yb3, yb4, yb5, yb6, yb7)
    STEP(12, ya0, ya1, ya2, ya3, ya4, ya5, ya6, ya7)
    STEP(13, yb0, yb1, yb2, yb3, yb4, yb5, yb6, yb7)
    STEP(14, ya0, ya1, ya2, ya3, ya4, ya5, ya6, ya7)
    STEP(15, yb0, yb1, yb2, yb3, yb4, yb5, yb6, yb7)
#undef STEP
#undef NONLIN
#undef UNP
#undef GATH
#undef WA
#undef WB

    unsigned short* ap = agg + (size_t)(base + qh * 4) * HDIM + colA;
    ap[0]        = (unsigned short)pkA0;
    ap[128]      = (unsigned short)(pkA0 >> 16);
    ap[256]      = (unsigned short)pkA1;
    ap[384]      = (unsigned short)(pkA1 >> 16);
    ap[16]       = (unsigned short)pkB0;
    ap[128 + 16] = (unsigned short)(pkB0 >> 16);
    ap[256 + 16] = (unsigned short)pkB1;
    ap[384 + 16] = (unsigned short)(pkB1 >> 16);
}

// ---- gemmCA: h_next = relu(agg.wl^T + h.wr^T + bl) + Xih next, 32 nodes ----
__global__ __launch_bounds__(256) void gemmCA_kernel(
        const unsigned short* __restrict__ agg, const unsigned short* __restrict__ hcur,
        const unsigned short* __restrict__ wl, const unsigned short* __restrict__ wr,
        const float* __restrict__ bl, const unsigned short* __restrict__ wih,
        const float* __restrict__ biasc, unsigned short* __restrict__ hnext,
        unsigned short* __restrict__ xihb) {
    __shared__ unsigned short htile[32][136];
    const int lane = threadIdx.x & 63, wv = threadIdx.x >> 6;
    const int cl = lane & 15, qh = lane >> 4, k8 = qh * 8;
    const int mbase = blockIdx.x * 32;

    bf16x8 bA0[4], bA1[4], bH0[4], bH1[4];
#pragma unroll
    for (int kt = 0; kt < 4; ++kt) {
        bA0[kt] = *(const bf16x8*)(agg  + (size_t)(mbase + cl) * HDIM + kt * 32 + k8);
        bA1[kt] = *(const bf16x8*)(agg  + (size_t)(mbase + 16 + cl) * HDIM + kt * 32 + k8);
        bH0[kt] = *(const bf16x8*)(hcur + (size_t)(mbase + cl) * HDIM + kt * 32 + k8);
        bH1[kt] = *(const bf16x8*)(hcur + (size_t)(mbase + 16 + cl) * HDIM + kt * 32 + k8);
    }
#pragma unroll
    for (int nt = 0; nt < 2; ++nt) {
        const int col = wv * 32 + nt * 16 + cl;
        f32x4 acc0 = {0.f, 0.f, 0.f, 0.f}, acc1 = {0.f, 0.f, 0.f, 0.f};
#pragma unroll
        for (int kt = 0; kt < 4; ++kt) {
            bf16x8 w = *(const bf16x8*)(wl + col * HDIM + kt * 32 + k8);
            acc0 = mfma16(bA0[kt], w, acc0);
            acc1 = mfma16(bA1[kt], w, acc1);
        }
#pragma unroll
        for (int kt = 0; kt < 4; ++kt) {
            bf16x8 w = *(const bf16x8*)(wr + col * HDIM + kt * 32 + k8);
            acc0 = mfma16(bH0[kt], w, acc0);
            acc1 = mfma16(bH1[kt], w, acc1);
        }
        float bias = bl[col];
#pragma unroll
        for (int r = 0; r < 4; ++r) {
            unsigned short v0 = f2bf(fmaxf(acc0[r] + bias, 0.f));
            unsigned short v1 = f2bf(fmaxf(acc1[r] + bias, 0.f));
            hnext[(size_t)(mbase + qh * 4 + r) * HDIM + col] = v0;
            hnext[(size_t)(mbase + 16 + qh * 4 + r) * HDIM + col] = v1;
            htile[qh * 4 + r][col] = v0;
            htile[16 + qh * 4 + r][col] = v1;
        }
    }
    __syncthreads();

    phaseA2(htile, wih, biasc, xihb, mbase, cl, qh, k8, wv);
}

// ---- gemmCF: out = agg.wl^T + h.wr^T + bl (f32), 32 nodes ------------------
__global__ __launch_bounds__(256) void gemmCF_kernel(
        const unsigned short* __restrict__ agg, const unsigned short* __restrict__ hcur,
        const unsigned short* __restrict__ wl, const unsigned short* __restrict__ wr,
        const float* __restrict__ bl, float* __restrict__ fout) {
    const int lane = threadIdx.x & 63, wv = threadIdx.x >> 6;
    const int cl = lane & 15, qh = lane >> 4, k8 = qh * 8;
    const int mbase = blockIdx.x * 32;

    bf16x8 bA0[4], bA1[4], bH0[4], bH1[4];
#pragma unroll
    for (int kt = 0; kt < 4; ++kt) {
        bA0[kt] = *(const bf16x8*)(agg  + (size_t)(mbase + cl) * HDIM + kt * 32 + k8);
        bA1[kt] = *(const bf16x8*)(agg  + (size_t)(mbase + 16 + cl) * HDIM + kt * 32 + k8);
        bH0[kt] = *(const bf16x8*)(hcur + (size_t)(mbase + cl) * HDIM + kt * 32 + k8);
        bH1[kt] = *(const bf16x8*)(hcur + (size_t)(mbase + 16 + cl) * HDIM + kt * 32 + k8);
    }
#pragma unroll
    for (int nt = 0; nt < 2; ++nt) {
        const int col = wv * 32 + nt * 16 + cl;
        f32x4 acc0 = {0.f, 0.f, 0.f, 0.f}, acc1 = {0.f, 0.f, 0.f, 0.f};
#pragma unroll
        for (int kt = 0; kt < 4; ++kt) {
            bf16x8 w = *(const bf16x8*)(wl + col * HDIM + kt * 32 + k8);
            acc0 = mfma16(bA0[kt], w, acc0);
            acc1 = mfma16(bA1[kt], w, acc1);
        }
#pragma unroll
        for (int kt = 0; kt < 4; ++kt) {
            bf16x8 w = *(const bf16x8*)(wr + col * HDIM + kt * 32 + k8);
            acc0 = mfma16(bH0[kt], w, acc0);
            acc1 = mfma16(bH1[kt], w, acc1);
        }
        float bias = bl[col];
#pragma unroll
        for (int r = 0; r < 4; ++r) {
            fout[(size_t)(mbase + qh * 4 + r) * HDIM + col] = acc0[r] + bias;
            fout[(size_t)(mbase + 16 + qh * 4 + r) * HDIM + col] = acc1[r] + bias;
        }
    }
}

// ---------------- host ------------------------------------------------------
extern "C" void kernel_launch(void* const* d_in, const int* in_sizes, int n_in,
                              void* d_out, int out_size, void* d_ws, size_t ws_size,
                              hipStream_t stream) {
    (void)in_sizes; (void)n_in; (void)out_size; (void)ws_size;

    const float* x     = (const float*)d_in[0];
    const int*   types = (const int*)d_in[1];
    const int*   esrc  = (const int*)d_in[2];
    const float* emb   = (const float*)d_in[4];

    char* ws = (char*)d_ws;
    unsigned short* hA   = (unsigned short*)ws; ws += (size_t)NN * HDIM * 2;
    unsigned short* hB   = (unsigned short*)ws; ws += (size_t)NN * HDIM * 2;
    unsigned short* agg  = (unsigned short*)ws; ws += (size_t)NN * HDIM * 2;
    unsigned short* xihb = (unsigned short*)ws; ws += (size_t)NN * GDIM * 2;
    unsigned short* wbf  = (unsigned short*)ws; ws += (size_t)3 * 163840 * 2;
    float*          bc   = (float*)ws;          // 3 x 512 f32

    unsigned short *wihb[3], *whhb[3], *wlb[3], *wrb[3];
    float* bcl[3];
    CvtArgs ca;
    for (int l = 0; l < 3; ++l) {
        unsigned short* lb = wbf + (size_t)l * 163840;
        wihb[l] = lb;
        whhb[l] = lb + 65536;
        wlb[l]  = lb + 131072;
        wrb[l]  = lb + 147456;
        bcl[l]  = bc + l * 512;
        ca.wih[l] = (const float*)d_in[5 + 7 * l + 0];
        ca.whh[l] = (const float*)d_in[5 + 7 * l + 1];
        ca.bih[l] = (const float*)d_in[5 + 7 * l + 2];
        ca.bhh[l] = (const float*)d_in[5 + 7 * l + 3];
        ca.wl[l]  = (const float*)d_in[5 + 7 * l + 4];
        ca.wr[l]  = (const float*)d_in[5 + 7 * l + 6];
        ca.dih[l] = wihb[l]; ca.dhh[l] = whhb[l]; ca.dl[l] = wlb[l]; ca.dr[l] = wrb[l];
        ca.dbias[l] = bcl[l];
    }
    cvt_kernel<<<1926, 256, 0, stream>>>(ca);

    gemmA0_kernel<<<NN / 32, 256, 0, stream>>>(x, types, emb, wihb[0], bcl[0], hA, xihb);

    unsigned short* hc = hA;
    unsigned short* hn = hB;
    for (int l = 0; l < 3; ++l) {
        const float* bl = (const float*)d_in[5 + 7 * l + 5];
        lstm_kernel<<<NN / 16, 256, 0, stream>>>(xihb, whhb[l], esrc, agg);
        if (l < 2) {
            gemmCA_kernel<<<NN / 32, 256, 0, stream>>>(
                agg, hc, wlb[l], wrb[l], bl, wihb[l + 1], bcl[l + 1], hn, xihb);
            unsigned short* t = hc; hc = hn; hn = t;
        } else {
            gemmCF_kernel<<<NN / 32, 256, 0, stream>>>(
                agg, hc, wlb[l], wrb[l], bl, (float*)d_out);
        }
    }
}